// Round 1
// baseline (116429.871 us; speedup 1.0000x reference)
//
#include <hip/hip_runtime.h>
#include <math.h>

// Problem dims (fixed)
#define T_SEQ 4096
#define DIN   64
#define DM    1024
#define G4    4096              // 4*DM gate rows
#define LSTRIDE_W ((size_t)G4 * DM)   // per-layer Wih/Whh stride
#define LSTRIDE_B ((size_t)G4)        // per-layer bias stride

static constexpr unsigned MAGIC = 0x5A5A5A5Au;  // != 0xAAAAAAAA poison

__device__ __forceinline__ float sigmoidf_(float x) {
    return 1.0f / (1.0f + __expf(-x));
}
__device__ __forceinline__ float tanhf_(float x) {
    float ax = fabsf(x);
    float e  = __expf(-2.0f * ax);
    float t  = (1.0f - e) / (1.0f + e);
    return copysignf(t, x);
}
__device__ __forceinline__ float lrelu_(float x) {
    return x > 0.0f ? x : 0.01f * x;
}

// ---------------------------------------------------------------------------
// K1: x[t,d] = leaky_relu(sum_k inp[t,k]*W1[d,k] + b1[d]);  grid=4096, block=256
// ---------------------------------------------------------------------------
__global__ __launch_bounds__(256) void k_input(const float* __restrict__ inp,
                                               const float* __restrict__ W1,
                                               const float* __restrict__ b1,
                                               float* __restrict__ x) {
    __shared__ float s_in[DIN];
    const int t   = blockIdx.x;
    const int tid = threadIdx.x;
    if (tid < DIN) s_in[tid] = inp[(size_t)t * DIN + tid];
    __syncthreads();
#pragma unroll
    for (int q = 0; q < 4; q++) {
        const int d = tid + q * 256;
        const float4* wr = (const float4*)(W1 + (size_t)d * DIN);
        float acc = 0.0f;
#pragma unroll
        for (int e = 0; e < 16; e++) {
            float4 w = wr[e];
            acc += w.x * s_in[e * 4 + 0] + w.y * s_in[e * 4 + 1] +
                   w.z * s_in[e * 4 + 2] + w.w * s_in[e * 4 + 3];
        }
        acc += b1[d];
        x[(size_t)t * DM + d] = lrelu_(acc);
    }
}

// ---------------------------------------------------------------------------
// K2/K4: C[m,n] = sum_k A[m,k]*B[n,k] + (bih[n]+bhh[n])
// A: 4096x1024, B: 4096x1024 (gate-row major), C: 4096x4096
// 128x128 tile, BK=16, 256 threads, 8x8 per thread.
// ---------------------------------------------------------------------------
__global__ __launch_bounds__(256) void k_gemm(const float* __restrict__ A,
                                              const float* __restrict__ B,
                                              const float* __restrict__ bih,
                                              const float* __restrict__ bhh,
                                              float* __restrict__ C) {
    const int K = DM;
    __shared__ float As[16][132];   // k-major, padded (132*4B = 16*33: float4 ok)
    __shared__ float Bs[16][132];
    const int tid = threadIdx.x;
    const int m0 = blockIdx.y * 128, n0 = blockIdx.x * 128;
    const int tx = tid & 15, ty = tid >> 4;
    const int lr = tid >> 1;          // 0..127 tile row to load
    const int lc = (tid & 1) * 8;     // 0 or 8

    float acc[8][8] = {};
    const float4* ag = (const float4*)(A + (size_t)(m0 + lr) * K + lc);
    const float4* bg = (const float4*)(B + (size_t)(n0 + lr) * K + lc);

    for (int k0 = 0; k0 < K; k0 += 16) {
        float4 a0 = ag[0], a1 = ag[1];
        float4 b0 = bg[0], b1v = bg[1];
        ag += 4; bg += 4;
        __syncthreads();
        As[lc + 0][lr] = a0.x; As[lc + 1][lr] = a0.y; As[lc + 2][lr] = a0.z; As[lc + 3][lr] = a0.w;
        As[lc + 4][lr] = a1.x; As[lc + 5][lr] = a1.y; As[lc + 6][lr] = a1.z; As[lc + 7][lr] = a1.w;
        Bs[lc + 0][lr] = b0.x; Bs[lc + 1][lr] = b0.y; Bs[lc + 2][lr] = b0.z; Bs[lc + 3][lr] = b0.w;
        Bs[lc + 4][lr] = b1v.x; Bs[lc + 5][lr] = b1v.y; Bs[lc + 6][lr] = b1v.z; Bs[lc + 7][lr] = b1v.w;
        __syncthreads();
#pragma unroll
        for (int k = 0; k < 16; k++) {
            float a[8], b[8];
            *(float4*)&a[0] = *(const float4*)&As[k][ty * 8 + 0];
            *(float4*)&a[4] = *(const float4*)&As[k][ty * 8 + 4];
            *(float4*)&b[0] = *(const float4*)&Bs[k][tx * 8 + 0];
            *(float4*)&b[4] = *(const float4*)&Bs[k][tx * 8 + 4];
#pragma unroll
            for (int i = 0; i < 8; i++)
#pragma unroll
                for (int j = 0; j < 8; j++)
                    acc[i][j] += a[i] * b[j];
        }
    }
    float bj[8];
#pragma unroll
    for (int j = 0; j < 8; j++) {
        int n = n0 + tx * 8 + j;
        bj[j] = bih[n] + bhh[n];
    }
#pragma unroll
    for (int i = 0; i < 8; i++) {
        float4 v0, v1;
        v0.x = acc[i][0] + bj[0]; v0.y = acc[i][1] + bj[1];
        v0.z = acc[i][2] + bj[2]; v0.w = acc[i][3] + bj[3];
        v1.x = acc[i][4] + bj[4]; v1.y = acc[i][5] + bj[5];
        v1.z = acc[i][6] + bj[6]; v1.w = acc[i][7] + bj[7];
        float* cp = C + (size_t)(m0 + ty * 8 + i) * G4 + n0 + tx * 8;
        *(float4*)(cp + 0) = v0;
        *(float4*)(cp + 4) = v1;
    }
}

// ---------------------------------------------------------------------------
// K3/K5: sequential LSTM scan. grid=256 WGs x 256 threads.
// WG w owns h-indices [4w, 4w+4) -> 16 gate rows {g*1024 + 4w + s}.
// thread: rs = tid>>4 (row_sub: g=rs>>2, s=rs&3), ck = tid&15 (k-chunk of 64).
// Whh row-chunk (64 fp32) lives in registers for the whole scan.
// Cross-WG exchange: hbuf[t] (t=1..T) + per-(t,WG) flag, relaxed/acquire/release.
// ---------------------------------------------------------------------------
__global__ __launch_bounds__(256) void k_scan(const float* __restrict__ xg,
                                              const float* __restrict__ Whh,
                                              float* hbuf,
                                              unsigned* flags,
                                              float* out) {
    const int tid = threadIdx.x;
    const int w   = blockIdx.x;
    const int rs  = tid >> 4;
    const int ck  = tid & 15;
    const int g   = rs >> 2, s = rs & 3;
    const int r   = g * DM + w * 4 + s;       // global gate row

    __shared__ float hl[16 * 68];             // h staged, 68-stride pad per 64-chunk
    __shared__ float gp[16];                  // 16 gate preactivations

    // Preload weights: Whh[r][ck*64 .. +64) into registers
    float wreg[64];
    {
        const float4* wp = (const float4*)(Whh + (size_t)r * DM + ck * 64);
#pragma unroll
        for (int e = 0; e < 16; e++) {
            float4 v = wp[e];
            wreg[e * 4 + 0] = v.x; wreg[e * 4 + 1] = v.y;
            wreg[e * 4 + 2] = v.z; wreg[e * 4 + 3] = v.w;
        }
    }

    const int c4 = tid >> 4;                  // chunk of this thread's stage slot
    const int e4 = (tid & 15) * 4;            // offset within chunk
    float c_state = 0.0f, h_last = 0.0f;

    for (int t = 0; t < T_SEQ; t++) {
        // prefetch xg for this step (independent of the poll)
        float xgv = 0.0f;
        if (ck == 0) xgv = xg[(size_t)t * G4 + r];

        if (t == 0) {
            float4 z; z.x = z.y = z.z = z.w = 0.0f;
            *(float4*)&hl[c4 * 68 + e4] = z;
        } else {
            // wait until all 256 producer WGs published h_t
            int ok;
            do {
                unsigned f = __hip_atomic_load(&flags[(size_t)t * 256 + tid],
                                               __ATOMIC_RELAXED, __HIP_MEMORY_SCOPE_AGENT);
                ok = (f == MAGIC);
            } while (!__syncthreads_and(ok));
            __builtin_amdgcn_fence(__ATOMIC_ACQUIRE, "agent");
            float4 hv = *(const float4*)&hbuf[(size_t)t * DM + tid * 4];
            *(float4*)&hl[c4 * 68 + e4] = hv;
        }
        __syncthreads();

        // dot: wreg[0..64) * h[ck*64 .. +64)
        const float* hp = &hl[ck * 68];
        float a0 = 0.f, a1 = 0.f, a2 = 0.f, a3 = 0.f;
#pragma unroll
        for (int u = 0; u < 16; u++) {
            float4 hv = *(const float4*)&hp[u * 4];
            a0 += wreg[u * 4 + 0] * hv.x;
            a1 += wreg[u * 4 + 1] * hv.y;
            a2 += wreg[u * 4 + 2] * hv.z;
            a3 += wreg[u * 4 + 3] * hv.w;
        }
        float acc = (a0 + a1) + (a2 + a3);
        // reduce across the 16 k-chunks (consecutive lanes)
        acc += __shfl_xor(acc, 1, 16);
        acc += __shfl_xor(acc, 2, 16);
        acc += __shfl_xor(acc, 4, 16);
        acc += __shfl_xor(acc, 8, 16);
        if (ck == 0) gp[rs] = xgv + acc;
        __syncthreads();

        // gate combine: threads 0..3 own h-index s = tid
        if (tid < 4) {
            float i_ = gp[0 + tid];
            float f_ = gp[4 + tid];
            float g_ = gp[8 + tid];
            float o_ = gp[12 + tid];
            c_state = sigmoidf_(f_) * c_state + sigmoidf_(i_) * tanhf_(g_);
            float h = sigmoidf_(o_) * tanhf_(c_state);
            h_last = h;
            __hip_atomic_store(&hbuf[(size_t)(t + 1) * DM + w * 4 + tid], h,
                               __ATOMIC_RELAXED, __HIP_MEMORY_SCOPE_AGENT);
            if (tid == 0)
                __hip_atomic_store(&flags[(size_t)(t + 1) * 256 + w], MAGIC,
                                   __ATOMIC_RELEASE, __HIP_MEMORY_SCOPE_AGENT);
        }
        __syncthreads();
    }

    if (out != nullptr && tid < 4) {
        out[w * 4 + tid] = lrelu_(h_last);
    }
}

// ---------------------------------------------------------------------------
extern "C" void kernel_launch(void* const* d_in, const int* in_sizes, int n_in,
                              void* d_out, int out_size, void* d_ws, size_t ws_size,
                              hipStream_t stream) {
    const float* inp = (const float*)d_in[0];   // 4096 x 64
    const float* W1  = (const float*)d_in[1];   // 1024 x 64
    const float* b1  = (const float*)d_in[2];   // 1024
    const float* Wih = (const float*)d_in[3];   // 2 x 4096 x 1024
    const float* Whh = (const float*)d_in[4];   // 2 x 4096 x 1024
    const float* bih = (const float*)d_in[5];   // 2 x 4096
    const float* bhh = (const float*)d_in[6];   // 2 x 4096
    float* out = (float*)d_out;                 // 1024

    // workspace layout (fp32 elements)
    float* x   = (float*)d_ws;                       // 4096*1024
    float* xg  = x  + (size_t)T_SEQ * DM;            // 4096*4096 (reused by both layers)
    float* hb1 = xg + (size_t)T_SEQ * G4;            // 4097*1024
    unsigned* fl1 = (unsigned*)(hb1 + (size_t)(T_SEQ + 1) * DM);   // 4097*256
    float* hb2 = (float*)(fl1 + (size_t)(T_SEQ + 1) * 256);        // 4097*1024
    unsigned* fl2 = (unsigned*)(hb2 + (size_t)(T_SEQ + 1) * DM);   // 4097*256
    (void)in_sizes; (void)n_in; (void)out_size; (void)ws_size;

    // Phase 1: input projection
    k_input<<<dim3(T_SEQ), dim3(256), 0, stream>>>(inp, W1, b1, x);

    // Phase 2: xg1 = x @ Wih0^T + b0
    k_gemm<<<dim3(32, 32), dim3(256), 0, stream>>>(x, Wih, bih, bhh, xg);

    // Phase 3: layer-0 scan (writes hb1[1..T])
    k_scan<<<dim3(256), dim3(256), 0, stream>>>(xg, Whh, hb1, fl1, nullptr);

    // Phase 4: xg2 = hs1 @ Wih1^T + b1sum   (hs1 rows are hb1[1..T])
    k_gemm<<<dim3(32, 32), dim3(256), 0, stream>>>(hb1 + DM, Wih + LSTRIDE_W,
                                                   bih + LSTRIDE_B, bhh + LSTRIDE_B, xg);

    // Phase 5: layer-1 scan, final h -> leaky_relu -> out
    k_scan<<<dim3(256), dim3(256), 0, stream>>>(xg, Whh + LSTRIDE_W, hb2, fl2, out);
}

// Round 2
// 60557.385 us; speedup vs baseline: 1.9226x; 1.9226x over previous
//
#include <hip/hip_runtime.h>
#include <math.h>

// Problem dims (fixed)
#define T_SEQ 4096
#define DIN   64
#define DM    1024
#define G4    4096              // 4*DM gate rows
#define LSTRIDE_W ((size_t)G4 * DM)   // per-layer Wih/Whh stride
#define LSTRIDE_B ((size_t)G4)        // per-layer bias stride

static constexpr unsigned MAGIC = 0x5A5A5A5Au;  // != 0xAAAAAAAA poison

__device__ __forceinline__ float sigmoidf_(float x) {
    return 1.0f / (1.0f + __expf(-x));
}
__device__ __forceinline__ float tanhf_(float x) {
    float ax = fabsf(x);
    float e  = __expf(-2.0f * ax);
    float t  = (1.0f - e) / (1.0f + e);
    return copysignf(t, x);
}
__device__ __forceinline__ float lrelu_(float x) {
    return x > 0.0f ? x : 0.01f * x;
}

// ---------------------------------------------------------------------------
// K1: x[t,d] = leaky_relu(sum_k inp[t,k]*W1[d,k] + b1[d]);  grid=4096, block=256
// ---------------------------------------------------------------------------
__global__ __launch_bounds__(256) void k_input(const float* __restrict__ inp,
                                               const float* __restrict__ W1,
                                               const float* __restrict__ b1,
                                               float* __restrict__ x) {
    __shared__ float s_in[DIN];
    const int t   = blockIdx.x;
    const int tid = threadIdx.x;
    if (tid < DIN) s_in[tid] = inp[(size_t)t * DIN + tid];
    __syncthreads();
#pragma unroll
    for (int q = 0; q < 4; q++) {
        const int d = tid + q * 256;
        const float4* wr = (const float4*)(W1 + (size_t)d * DIN);
        float acc = 0.0f;
#pragma unroll
        for (int e = 0; e < 16; e++) {
            float4 w = wr[e];
            acc += w.x * s_in[e * 4 + 0] + w.y * s_in[e * 4 + 1] +
                   w.z * s_in[e * 4 + 2] + w.w * s_in[e * 4 + 3];
        }
        acc += b1[d];
        x[(size_t)t * DM + d] = lrelu_(acc);
    }
}

// ---------------------------------------------------------------------------
// K2/K4: C[m,n] = sum_k A[m,k]*B[n,k] + (bih[n]+bhh[n])
// 128x128 tile, BK=16, 256 threads, 8x8 per thread.
// ---------------------------------------------------------------------------
__global__ __launch_bounds__(256) void k_gemm(const float* __restrict__ A,
                                              const float* __restrict__ B,
                                              const float* __restrict__ bih,
                                              const float* __restrict__ bhh,
                                              float* __restrict__ C) {
    const int K = DM;
    __shared__ float As[16][132];
    __shared__ float Bs[16][132];
    const int tid = threadIdx.x;
    const int m0 = blockIdx.y * 128, n0 = blockIdx.x * 128;
    const int tx = tid & 15, ty = tid >> 4;
    const int lr = tid >> 1;
    const int lc = (tid & 1) * 8;

    float acc[8][8] = {};
    const float4* ag = (const float4*)(A + (size_t)(m0 + lr) * K + lc);
    const float4* bg = (const float4*)(B + (size_t)(n0 + lr) * K + lc);

    for (int k0 = 0; k0 < K; k0 += 16) {
        float4 a0 = ag[0], a1 = ag[1];
        float4 b0 = bg[0], b1v = bg[1];
        ag += 4; bg += 4;
        __syncthreads();
        As[lc + 0][lr] = a0.x; As[lc + 1][lr] = a0.y; As[lc + 2][lr] = a0.z; As[lc + 3][lr] = a0.w;
        As[lc + 4][lr] = a1.x; As[lc + 5][lr] = a1.y; As[lc + 6][lr] = a1.z; As[lc + 7][lr] = a1.w;
        Bs[lc + 0][lr] = b0.x; Bs[lc + 1][lr] = b0.y; Bs[lc + 2][lr] = b0.z; Bs[lc + 3][lr] = b0.w;
        Bs[lc + 4][lr] = b1v.x; Bs[lc + 5][lr] = b1v.y; Bs[lc + 6][lr] = b1v.z; Bs[lc + 7][lr] = b1v.w;
        __syncthreads();
#pragma unroll
        for (int k = 0; k < 16; k++) {
            float a[8], b[8];
            *(float4*)&a[0] = *(const float4*)&As[k][ty * 8 + 0];
            *(float4*)&a[4] = *(const float4*)&As[k][ty * 8 + 4];
            *(float4*)&b[0] = *(const float4*)&Bs[k][tx * 8 + 0];
            *(float4*)&b[4] = *(const float4*)&Bs[k][tx * 8 + 4];
#pragma unroll
            for (int i = 0; i < 8; i++)
#pragma unroll
                for (int j = 0; j < 8; j++)
                    acc[i][j] += a[i] * b[j];
        }
    }
    float bj[8];
#pragma unroll
    for (int j = 0; j < 8; j++) {
        int n = n0 + tx * 8 + j;
        bj[j] = bih[n] + bhh[n];
    }
#pragma unroll
    for (int i = 0; i < 8; i++) {
        float4 v0, v1;
        v0.x = acc[i][0] + bj[0]; v0.y = acc[i][1] + bj[1];
        v0.z = acc[i][2] + bj[2]; v0.w = acc[i][3] + bj[3];
        v1.x = acc[i][4] + bj[4]; v1.y = acc[i][5] + bj[5];
        v1.z = acc[i][6] + bj[6]; v1.w = acc[i][7] + bj[7];
        float* cp = C + (size_t)(m0 + ty * 8 + i) * G4 + n0 + tx * 8;
        *(float4*)(cp + 0) = v0;
        *(float4*)(cp + 4) = v1;
    }
}

// ---------------------------------------------------------------------------
// K3/K5: sequential LSTM scan. grid=256 WGs x 256 threads.
// WG w owns h-indices [4w, 4w+4) -> 16 gate rows {g*1024 + 4w + s}.
// Sync protocol (R2): per-thread relaxed spin on own flag (NO barrier in the
// poll loop), then relaxed agent-scope atomic loads of the 4 h-values that
// flag guards (cache-bypassing -> no acquire fence / buffer_inv needed).
// Producer: tid<4 relaxed agent stores (one wave instruction), tid==0 release
// flag store -- release's s_waitcnt vmcnt(0) covers the whole wave's stores.
// ---------------------------------------------------------------------------
__global__ __launch_bounds__(256) void k_scan(const float* __restrict__ xg,
                                              const float* __restrict__ Whh,
                                              float* hbuf,
                                              unsigned* flags,
                                              float* out) {
    const int tid = threadIdx.x;
    const int w   = blockIdx.x;
    const int rs  = tid >> 4;
    const int ck  = tid & 15;
    const int g   = rs >> 2, s = rs & 3;
    const int r   = g * DM + w * 4 + s;       // global gate row

    __shared__ float hl[16 * 68];             // h staged, 68-stride pad per 64-chunk
    __shared__ float gp[16];                  // 16 gate preactivations

    // Preload weights: Whh[r][ck*64 .. +64) into registers
    float wreg[64];
    {
        const float4* wp = (const float4*)(Whh + (size_t)r * DM + ck * 64);
#pragma unroll
        for (int e = 0; e < 16; e++) {
            float4 v = wp[e];
            wreg[e * 4 + 0] = v.x; wreg[e * 4 + 1] = v.y;
            wreg[e * 4 + 2] = v.z; wreg[e * 4 + 3] = v.w;
        }
    }

    // LDS stage slot for this thread: h-indices [tid*4, tid*4+4)
    const int slot = (tid >> 4) * 68 + (tid & 15) * 4;
    float c_state = 0.0f, h_last = 0.0f;

    // t=0: h is zero
    {
        float4 z; z.x = z.y = z.z = z.w = 0.0f;
        *(float4*)&hl[slot] = z;
    }

    for (int t = 0; t < T_SEQ; t++) {
        // prefetch xg for this step (independent of the poll)
        float xgv = 0.0f;
        if (ck == 0) xgv = xg[(size_t)t * G4 + r];

        if (t > 0) {
            // spin on own flag: WG `tid` published h[t][tid*4 .. +4)
            const unsigned* fp = &flags[(size_t)t * 256 + tid];
            while (__hip_atomic_load(fp, __ATOMIC_RELAXED,
                                     __HIP_MEMORY_SCOPE_AGENT) != MAGIC) { }
            const float* hp = &hbuf[(size_t)t * DM + tid * 4];
            float h0 = __hip_atomic_load(hp + 0, __ATOMIC_RELAXED, __HIP_MEMORY_SCOPE_AGENT);
            float h1 = __hip_atomic_load(hp + 1, __ATOMIC_RELAXED, __HIP_MEMORY_SCOPE_AGENT);
            float h2 = __hip_atomic_load(hp + 2, __ATOMIC_RELAXED, __HIP_MEMORY_SCOPE_AGENT);
            float h3 = __hip_atomic_load(hp + 3, __ATOMIC_RELAXED, __HIP_MEMORY_SCOPE_AGENT);
            hl[slot + 0] = h0; hl[slot + 1] = h1;
            hl[slot + 2] = h2; hl[slot + 3] = h3;
        }
        __syncthreads();

        // dot: wreg[0..64) * h[ck*64 .. +64)
        const float* hp = &hl[ck * 68];
        float a0 = 0.f, a1 = 0.f, a2 = 0.f, a3 = 0.f;
#pragma unroll
        for (int u = 0; u < 16; u++) {
            float4 hv = *(const float4*)&hp[u * 4];
            a0 += wreg[u * 4 + 0] * hv.x;
            a1 += wreg[u * 4 + 1] * hv.y;
            a2 += wreg[u * 4 + 2] * hv.z;
            a3 += wreg[u * 4 + 3] * hv.w;
        }
        float acc = (a0 + a1) + (a2 + a3);
        // reduce across the 16 k-chunks (consecutive lanes)
        acc += __shfl_xor(acc, 1, 16);
        acc += __shfl_xor(acc, 2, 16);
        acc += __shfl_xor(acc, 4, 16);
        acc += __shfl_xor(acc, 8, 16);
        if (ck == 0) gp[rs] = xgv + acc;
        __syncthreads();

        // gate combine: threads 0..3 own h-index s = tid (all in wave 0)
        if (tid < 4) {
            float i_ = gp[0 + tid];
            float f_ = gp[4 + tid];
            float g_ = gp[8 + tid];
            float o_ = gp[12 + tid];
            c_state = sigmoidf_(f_) * c_state + sigmoidf_(i_) * tanhf_(g_);
            float h = sigmoidf_(o_) * tanhf_(c_state);
            h_last = h;
            __hip_atomic_store(&hbuf[(size_t)(t + 1) * DM + w * 4 + tid], h,
                               __ATOMIC_RELAXED, __HIP_MEMORY_SCOPE_AGENT);
            if (tid == 0)
                __hip_atomic_store(&flags[(size_t)(t + 1) * 256 + w], MAGIC,
                                   __ATOMIC_RELEASE, __HIP_MEMORY_SCOPE_AGENT);
        }
        __syncthreads();
    }

    if (out != nullptr && tid < 4) {
        out[w * 4 + tid] = lrelu_(h_last);
    }
}

// ---------------------------------------------------------------------------
extern "C" void kernel_launch(void* const* d_in, const int* in_sizes, int n_in,
                              void* d_out, int out_size, void* d_ws, size_t ws_size,
                              hipStream_t stream) {
    const float* inp = (const float*)d_in[0];   // 4096 x 64
    const float* W1  = (const float*)d_in[1];   // 1024 x 64
    const float* b1  = (const float*)d_in[2];   // 1024
    const float* Wih = (const float*)d_in[3];   // 2 x 4096 x 1024
    const float* Whh = (const float*)d_in[4];   // 2 x 4096 x 1024
    const float* bih = (const float*)d_in[5];   // 2 x 4096
    const float* bhh = (const float*)d_in[6];   // 2 x 4096
    float* out = (float*)d_out;                 // 1024

    // workspace layout (fp32 elements)
    float* x   = (float*)d_ws;                       // 4096*1024
    float* xg  = x  + (size_t)T_SEQ * DM;            // 4096*4096 (reused by both layers)
    float* hb1 = xg + (size_t)T_SEQ * G4;            // 4097*1024
    unsigned* fl1 = (unsigned*)(hb1 + (size_t)(T_SEQ + 1) * DM);   // 4097*256
    float* hb2 = (float*)(fl1 + (size_t)(T_SEQ + 1) * 256);        // 4097*1024
    unsigned* fl2 = (unsigned*)(hb2 + (size_t)(T_SEQ + 1) * DM);   // 4097*256
    (void)in_sizes; (void)n_in; (void)out_size; (void)ws_size;

    // Phase 1: input projection
    k_input<<<dim3(T_SEQ), dim3(256), 0, stream>>>(inp, W1, b1, x);

    // Phase 2: xg1 = x @ Wih0^T + b0
    k_gemm<<<dim3(32, 32), dim3(256), 0, stream>>>(x, Wih, bih, bhh, xg);

    // Phase 3: layer-0 scan (writes hb1[1..T])
    k_scan<<<dim3(256), dim3(256), 0, stream>>>(xg, Whh, hb1, fl1, nullptr);

    // Phase 4: xg2 = hs1 @ Wih1^T + b1sum   (hs1 rows are hb1[1..T])
    k_gemm<<<dim3(32, 32), dim3(256), 0, stream>>>(hb1 + DM, Wih + LSTRIDE_W,
                                                   bih + LSTRIDE_B, bhh + LSTRIDE_B, xg);

    // Phase 5: layer-1 scan, final h -> leaky_relu -> out
    k_scan<<<dim3(256), dim3(256), 0, stream>>>(xg, Whh + LSTRIDE_W, hb2, fl2, out);
}